// Round 9
// baseline (122.479 us; speedup 1.0000x reference)
//
#include <hip/hip_runtime.h>
#include <math.h>

#define Wd 256
#define Hd 256
#define KW 11
#define OUT_R 26              // output rows per block; stream 36 = 9 steps x 4 rows
#define BLOCK 256

typedef float v2f __attribute__((ext_vector_type(2)));

__device__ __forceinline__ float rfl(float v) {
    return __int_as_float(__builtin_amdgcn_readfirstlane(__float_as_int(v)));
}

// Packed dual FP32 FMA (VOP3P): {acc.lo,acc.hi} += {x.lo,x.hi}*{w.lo,w.hi}.
// All three sources MUST be 64-bit VGPR pairs (R8 failed: a 32-bit SGPR
// src is an invalid VOP3P operand on gfx950). Weights are pre-broadcast
// into packed VGPR pairs {w,w} once in the prologue.
// Bitwise-identical IEEE fma per half (R7 geometry passed absmax=0).
__device__ __forceinline__ void pk_fma(v2f &acc, v2f x, v2f w) {
    asm("v_pk_fma_f32 %0, %1, %2, %0"
        : "+v"(acc) : "v"(x), "v"(w));
}

// lgkmcnt-only barrier: LDS handoff without draining global prefetch (R2/R5).
__device__ __forceinline__ void barrier_lds_only() {
    asm volatile("s_waitcnt lgkmcnt(0)\n\ts_barrier" ::: "memory");
}

// R9: PACKED-FP32 arithmetic on the R7 4-row-step structure (R8 fixed).
//
// Invariance ledger (~42-46us): barrier flavor (R2), block supply (R4),
// prefetch depth (R5 -4%), skew (R6), step size / LDS layout (R7), bank
// conflicts (43K vs 1.29M: no effect), memory residency (L3-resident
// dispatch == HBM dispatch). The only variable that ever moved duration:
// total dynamic instruction count (R4: +27% inst -> +20% time; R7: same
// inst -> same time). VALUBusy 40% == the instruction stream itself
// (5.6 waves/SIMD x 3.5K inst x 2cy ~= 40K of 100K cycles). So: halve the
// FMA stream with v_pk_fma_f32 (hipcc never auto-packs fp32).
//
// launch_bounds(256,3): natural fit (R7: VGPR 56; +22 packed weights +
// dual accs ~= 100 < 170 budget). arg2>4 squeezes below need and spills
// 65-167MB (R1/R3) -- never.
__global__ __launch_bounds__(BLOCK, 3) void ssim_quad_kernel(
    const float* __restrict__ img1, const float* __restrict__ img2,
    const float* __restrict__ window, float* __restrict__ out, float scale)
{
    // {L = (mu1,mu2) partials, H = (x2+y2, xy) partials} per col per row.
    // res[emit row 0..3][col&3][col>>2 + 2]; idx 0,1,66,67 = zero halos.
    struct __align__(16) pkpair { v2f L; v2f H; };
    __shared__ pkpair res[4][4][68];              // 17.4 KB
    __shared__ float red[BLOCK / 64];

    const float C1 = 1e-4f, C2 = 9e-4f;
    const int t = threadIdx.x;
    const int band = blockIdx.x;     // 0..9 (band 9 partial: 22 rows)
    const int plane = blockIdx.y;    // 0..143
    const float* __restrict__ p1 = img1 + (size_t)plane * (Hd * Wd);
    const float* __restrict__ p2 = img2 + (size_t)plane * (Hd * Wd);

    // Separable 1D weights: packed {w,w} VGPR pairs for v_pk_fma_f32.
    v2f wp[KW];
    {
        float c = sqrtf(window[5 * KW + 5]);
        #pragma unroll
        for (int k = 0; k < KW; ++k) {
            float w = rfl(window[k * KW + 5] / c);
            wp[k].x = w; wp[k].y = w;
        }
    }

    // Zero column-halo cells (idx 0,1,66,67 of each [row][arr]); visible at
    // the first emit's barrier.
    if (t < 64) {
        int row = t >> 4, arr = (t >> 2) & 3, sel = t & 3;
        int idx = (sel < 2) ? sel : (64 + sel);
        pkpair z; z.L = (v2f){0.f, 0.f}; z.H = (v2f){0.f, 0.f};
        res[row][arr][idx] = z;
    }

    const int ghbase = band * OUT_R - 5;   // global row of stream index 0
    const int w = t >> 6, cp = t & 63;     // hconv: wave=row, 4 cols/thread

    v2f rngL[16], rngH[16];                // ring: L=(x,y), H=(x2+y2, xy)
    float acc = 0.f;

    auto ssim_term = [&](v2f L, v2f H) -> float {
        float mu1 = L.x, mu2 = L.y, sq = H.x, sp = H.y;
        float mu12 = mu1 * mu2;
        float musum = mu1 * mu1 + mu2 * mu2;
        float num = (2.f * mu12 + C1) * (2.f * (sp - mu12) + C2);
        float den = (musum + C1) * ((sq - musum) + C2);
        return num * __builtin_amdgcn_rcpf(den);
    };

    // initial 4-row load (stream rows 0..3); 1-deep prefetch thereafter
    float cx[4], cy[4];
    #pragma unroll
    for (int c = 0; c < 4; ++c) {
        int g = ghbase + c;
        bool ok = (unsigned)g < (unsigned)Hd;
        cx[c] = ok ? p1[(g << 8) + t] : 0.f;
        cy[c] = ok ? p2[(g << 8) + t] : 0.f;
    }

#define SSIM_STEP(PH, K, DOLOAD, DOEMIT) do {                                  \
    _Pragma("unroll")                                                          \
    for (int c = 0; c < 4; ++c) {          /* insert rows 4K..4K+3 */          \
        v2f eL, eH;                                                            \
        eL.x = cx[c]; eL.y = cy[c];                                            \
        eH.x = fmaf(cx[c], cx[c], cy[c] * cy[c]);                              \
        eH.y = cx[c] * cy[c];                                                  \
        rngL[4 * (PH) + c] = eL;                                               \
        rngH[4 * (PH) + c] = eH;                                               \
    }                                                                          \
    if (DOLOAD) {                          /* prefetch rows 4(K+1).. */        \
        _Pragma("unroll")                                                      \
        for (int c = 0; c < 4; ++c) {                                          \
            int g = ghbase + 4 * ((K) + 1) + c;                                \
            bool ok = (unsigned)g < (unsigned)Hd;                              \
            cx[c] = ok ? p1[(g << 8) + t] : 0.f;                               \
            cy[c] = ok ? p2[(g << 8) + t] : 0.f;                               \
        }                                                                      \
    }                                                                          \
    if (DOEMIT) {                                                              \
        _Pragma("unroll")                                                      \
        for (int c = 0; c < 4; ++c) {      /* vertical 11-tap, 4 rows */       \
            v2f aL = {0.f, 0.f}, aH = {0.f, 0.f};                              \
            _Pragma("unroll")                                                  \
            for (int m = 0; m < KW; ++m) {                                     \
                const int s = (4 * (PH) + 4 + c + m) & 15;                     \
                pk_fma(aL, rngL[s], wp[m]);                                    \
                pk_fma(aH, rngH[s], wp[m]);                                    \
            }                                                                  \
            pkpair av; av.L = aL; av.H = aH;                                   \
            res[c][t & 3][(t >> 2) + 2] = av;  /* col t, residue split */      \
        }                                                                      \
        barrier_lds_only();                                                    \
        {                                                                      \
            const int rr = 4 * (K) - 12 + w;   /* band row of wave w */        \
            if (rr < OUT_R && band * OUT_R + rr < Hd) {                        \
                v2f a0L = {0.f,0.f}, a0H = {0.f,0.f};                          \
                v2f a1L = {0.f,0.f}, a1H = {0.f,0.f};                          \
                v2f a2L = {0.f,0.f}, a2H = {0.f,0.f};                          \
                v2f a3L = {0.f,0.f}, a3H = {0.f,0.f};                          \
                _Pragma("unroll")                                              \
                for (int off = -5; off <= 8; ++off) {  /* cols 4cp+off */      \
                    pkpair v = res[w][(off) & 3][cp + ((off) >> 2) + 2];       \
                    if ((off) <= 5) {                                          \
                        pk_fma(a0L, v.L, wp[(off) + 5]);                       \
                        pk_fma(a0H, v.H, wp[(off) + 5]);                       \
                    }                                                          \
                    if ((off) >= -4 && (off) <= 6) {                           \
                        pk_fma(a1L, v.L, wp[(off) + 4]);                       \
                        pk_fma(a1H, v.H, wp[(off) + 4]);                       \
                    }                                                          \
                    if ((off) >= -3 && (off) <= 7) {                           \
                        pk_fma(a2L, v.L, wp[(off) + 3]);                       \
                        pk_fma(a2H, v.H, wp[(off) + 3]);                       \
                    }                                                          \
                    if ((off) >= -2) {                                         \
                        pk_fma(a3L, v.L, wp[(off) + 2]);                       \
                        pk_fma(a3H, v.H, wp[(off) + 2]);                       \
                    }                                                          \
                }                                                              \
                acc += ssim_term(a0L, a0H); acc += ssim_term(a1L, a1H);        \
                acc += ssim_term(a2L, a2H); acc += ssim_term(a3L, a3H);        \
            }                                                                  \
        }                                                                      \
        barrier_lds_only();                                                    \
    }                                                                          \
} while (0)

    #pragma unroll 1
    for (int kb = 0; kb < 2; ++kb) {       // k = 0..7; phase = kk (static)
        #pragma unroll
        for (int kk = 0; kk < 4; ++kk) {
            SSIM_STEP(kk, 4 * kb + kk, true, (4 * kb + kk) >= 3);
        }
    }
    SSIM_STEP(0, 8, false, true);          // k=8: insert streams 32..35, emit rows 20..23
    #pragma unroll
    for (int c = 0; c < 4; ++c) { cx[c] = 0.f; cy[c] = 0.f; }
    SSIM_STEP(1, 9, false, true);          // epilogue: zero streams 36..37, emit rows 24..25

#undef SSIM_STEP

    // --- block reduction + fused global reduce (atomic) ---
    #pragma unroll
    for (int off = 32; off > 0; off >>= 1)
        acc += __shfl_down(acc, off, 64);
    int wave = t >> 6;
    if ((t & 63) == 0) red[wave] = acc;
    barrier_lds_only();
    if (t == 0) {
        float partial = red[0] + red[1] + red[2] + red[3];
        float v = partial * scale;                 // scale = -1/count
        if (band == 0 && plane == 0) v += 1.0f;    // out = 1 - sum/count
        atomicAdd(out, v);
    }
}

extern "C" void kernel_launch(void* const* d_in, const int* in_sizes, int n_in,
                              void* d_out, int out_size, void* d_ws, size_t ws_size,
                              hipStream_t stream) {
    const float* img1   = (const float*)d_in[0];
    const float* img2   = (const float*)d_in[1];
    const float* window = (const float*)d_in[2];
    float* out = (float*)d_out;

    const int planes = 16 * 9;                     // 144
    const int bands = (Hd + OUT_R - 1) / OUT_R;    // 10 (last band 22 rows)

    hipMemsetAsync(out, 0, sizeof(float), stream);

    const float scale = -(float)(1.0 / ((double)planes * Hd * Wd));
    dim3 grid(bands, planes);
    ssim_quad_kernel<<<grid, BLOCK, 0, stream>>>(img1, img2, window, out, scale);
}